// Round 10
// baseline (505.734 us; speedup 1.0000x reference)
//
#include <hip/hip_runtime.h>
#include <hip/hip_bf16.h>
#include <hip/hip_cooperative_groups.h>
#include <math.h>

namespace cg = cooperative_groups;

#define N_TOK 4096
#define D_MODEL 1024
#define NHEAD 8
#define DKQ 16
#define DVH 64
#define QGW 80   // DK+DV columns per head
#define QGN 640  // H * 80
#define HD  512  // H * DV
#define TI  32   // attention: i-rows per tile
#define DC  64   // attention: j-chunk width
#define NCH_MAX 5
#define NBLK 640     // cooperative grid size
#define EPI_UNITS (3 * N_TOK / 4)   // 3072: h in {5,6,7}, 4 rows per unit

typedef __attribute__((ext_vector_type(8))) short short8;
typedef __attribute__((ext_vector_type(4))) float f32x4;

#define GLOAD_LDS16(gp, lp) \
  __builtin_amdgcn_global_load_lds((const __attribute__((address_space(1))) void*)(gp), \
                                   (__attribute__((address_space(3))) void*)(lp), 16, 0, 0)

struct Smem {
    union {
        float tile[32][33];                                   //  4.2 KB (pack)
        struct { __hip_bfloat16 As[128 * 32];
                 __hip_bfloat16 Bs[64 * 32]; } g;             // 12.3 KB (gemm)
        struct { float Q[TI][16]; float K[DC][16];
                 float V[DC][DVH]; float att[TI][68];
                 float soft[288]; } a;                        // 32.4 KB (attn)
    };
};

// ---------------------------------------------------------------------------
// pack unit: one 32x32 weight transpose+cast tile. b in [0,1792).
// ---------------------------------------------------------------------------
__device__ __forceinline__ void dev_pack_w(Smem& s, int b,
    const float* __restrict__ w_qg, const float* __restrict__ w_kv,
    const float* __restrict__ w_out, __hip_bfloat16* __restrict__ wqgT,
    __hip_bfloat16* __restrict__ wkvT, __hip_bfloat16* __restrict__ woutT, int t)
{
    const float* in; __hip_bfloat16* outp; int R, C, tb;
    if (b < 640)       { in = w_qg;  outp = wqgT;  R = 1024; C = 640;  tb = b; }
    else if (b < 1280) { in = w_kv;  outp = wkvT;  R = 1024; C = 640;  tb = b - 640; }
    else               { in = w_out; outp = woutT; R = 512;  C = 1024; tb = b - 1280; }
    int ctiles = C / 32;
    int bx = (tb % ctiles) * 32;
    int by = (tb / ctiles) * 32;
    int tx = t & 31, ty = t >> 5;

    __syncthreads();                 // LDS reuse guard across units
    #pragma unroll
    for (int j = 0; j < 32; j += 8)
        s.tile[j + ty][tx] = in[(size_t)(by + j + ty) * C + bx + tx];
    __syncthreads();
    #pragma unroll
    for (int j = 0; j < 32; j += 8)
        outp[(size_t)(bx + j + ty) * R + by + tx] =
            __float2bfloat16(s.tile[tx][j + ty]);
}

// ---------------------------------------------------------------------------
// GEMM tile: C[bm:bm+128, bn:bn+64] = A * Bt^T, BK=32, 4 waves. (R7-proven)
// ---------------------------------------------------------------------------
__device__ __forceinline__ void dev_gemm_tile(Smem& s,
    const __hip_bfloat16* __restrict__ A, const __hip_bfloat16* __restrict__ Bt,
    float* __restrict__ C, int Nb, int K, int bm, int bn, int t)
{
    int l = t & 63, w = t >> 6, wr = w >> 1, wc = w & 1;
    int srow = t >> 2, skc = (t & 3) * 8;
    const __hip_bfloat16* ga0 = A + (size_t)(bm + srow) * K + skc;
    const __hip_bfloat16* ga1 = A + (size_t)(bm + 64 + srow) * K + skc;
    const __hip_bfloat16* gb  = Bt + (size_t)(bn + srow) * K + skc;
    __hip_bfloat16* lA0 = &s.g.As[(t & ~63) * 8];
    __hip_bfloat16* lA1 = &s.g.As[2048 + (t & ~63) * 8];
    __hip_bfloat16* lB  = &s.g.Bs[(t & ~63) * 8];

    f32x4 acc[4][2] = {};
    int aro = (wr * 64 + (l & 15)) * 32 + (l >> 4) * 8;
    int bro = (wc * 32 + (l & 15)) * 32 + (l >> 4) * 8;

    for (int k0 = 0; k0 < K; k0 += 32) {
        GLOAD_LDS16(ga0 + k0, lA0);
        GLOAD_LDS16(ga1 + k0, lA1);
        GLOAD_LDS16(gb  + k0, lB);
        __syncthreads();

        short8 af[4], bf[2];
        #pragma unroll
        for (int m = 0; m < 4; ++m) af[m] = *(const short8*)&s.g.As[aro + m * 16 * 32];
        #pragma unroll
        for (int n = 0; n < 2; ++n) bf[n] = *(const short8*)&s.g.Bs[bro + n * 16 * 32];

        #pragma unroll
        for (int m = 0; m < 4; ++m)
            #pragma unroll
            for (int n = 0; n < 2; ++n)
                acc[m][n] = __builtin_amdgcn_mfma_f32_16x16x32_bf16(
                                af[m], bf[n], acc[m][n], 0, 0, 0);
        __syncthreads();
    }

    int crow = bm + wr * 64 + (l >> 4) * 4;
    int ccol = bn + wc * 32 + (l & 15);
    #pragma unroll
    for (int m = 0; m < 4; ++m)
        #pragma unroll
        for (int n = 0; n < 2; ++n)
            #pragma unroll
            for (int j = 0; j < 4; ++j)
                C[(size_t)(crow + m * 16 + j) * Nb + ccol + n * 16] = acc[m][n][j];
}

__device__ __forceinline__ void dev_gemm1_unit(Smem& s, int unit,
    const __hip_bfloat16* tokB, const __hip_bfloat16* wqgT,
    const __hip_bfloat16* wkvT, float* qg, float* kv, int t)
{
    int bnt = unit % 20;
    int bm  = (unit / 20) * 128;
    const __hip_bfloat16* Bt; float* C;
    if (bnt < 10) { Bt = wqgT; C = qg; } else { Bt = wkvT; C = kv; bnt -= 10; }
    dev_gemm_tile(s, tokB, Bt, C, QGN, D_MODEL, bm, bnt * 64, t);
}

__device__ __forceinline__ void dev_gemm2_unit(Smem& s, int unit,
    const __hip_bfloat16* Yb, const __hip_bfloat16* woutT, float* out, int t)
{
    dev_gemm_tile(s, Yb, woutT, out, D_MODEL, HD, (unit >> 4) * 128,
                  (unit & 15) * 64, t);
}

// ---------------------------------------------------------------------------
// attention chunk unit (R7-proven body). u = h*(128*NCH_MAX)+tile*NCH_MAX+slot
// ---------------------------------------------------------------------------
__device__ __forceinline__ void dev_attn_unit(Smem& s, int u,
    const float* __restrict__ qg, const float* __restrict__ kv,
    const float* __restrict__ log_window, const float* __restrict__ log_r,
    const float* __restrict__ log_hscale,
    float* __restrict__ Ypart, __hip_bfloat16* __restrict__ Yb, int t)
{
    int h    = u / (128 * NCH_MAX);
    int rem  = u - h * (128 * NCH_MAX);
    int tile = rem / NCH_MAX;
    int slot = rem - tile * NCH_MAX;
    int i0 = tile * TI;

    float w = expf(log_window[h]) + 1.f;
    float r = expf(log_r[h]) + 1.f;
    int dmax = (int)ceilf(w) - 1;
    int jstart = i0 - dmax; if (jstart < 0) jstart = 0;
    int nch = (i0 + TI - jstart + DC - 1) / DC;
    if (slot >= nch) return;          // uniform early-out (block-uniform)
    int j0 = jstart + slot * DC;

    __syncthreads();                  // LDS reuse guard across units

    const float PI = 3.14159265358979f;
    for (int d = t; d <= dmax; d += 256)
        s.a.soft[d] = 0.5f * (cosf(PI * (float)d / w) + 1.f);

    if (t < TI * 4) {
        int iq = t >> 2, c = (t & 3) * 4;
        float4 qv = *(const float4*)(qg + (size_t)(i0 + iq) * QGN + h * QGW + c);
        float sv = qv.x*qv.x + qv.y*qv.y + qv.z*qv.z + qv.w*qv.w;
        sv += __shfl_xor(sv, 1); sv += __shfl_xor(sv, 2);
        float inv = 1.f / fmaxf(sqrtf(sv), 1e-12f);
        qv.x *= inv; qv.y *= inv; qv.z *= inv; qv.w *= inv;
        *(float4*)&s.a.Q[iq][c] = qv;
    }
    {
        int jr = t >> 2, c = (t & 3) * 4;
        int j = j0 + jr;
        float4 kx = make_float4(0.f, 0.f, 0.f, 0.f);
        if (j < N_TOK)
            kx = *(const float4*)(kv + (size_t)j * QGN + h * QGW + c);
        float sv = kx.x*kx.x + kx.y*kx.y + kx.z*kx.z + kx.w*kx.w;
        sv += __shfl_xor(sv, 1); sv += __shfl_xor(sv, 2);
        float inv = 1.f / fmaxf(sqrtf(sv), 1e-12f);
        kx.x *= inv; kx.y *= inv; kx.z *= inv; kx.w *= inv;
        *(float4*)&s.a.K[jr][c] = kx;
    }
    #pragma unroll
    for (int kk = 0; kk < 4; ++kk) {
        int f = t + kk * 256;
        int jc = f >> 4, c = (f & 15) * 4;
        int j = j0 + jc;
        float4 vx = make_float4(0.f, 0.f, 0.f, 0.f);
        if (j < N_TOK)
            vx = *(const float4*)(kv + (size_t)j * QGN + h * QGW + DKQ + c);
        float sv = vx.x*vx.x + vx.y*vx.y + vx.z*vx.z + vx.w*vx.w;
        sv += __shfl_xor(sv, 1); sv += __shfl_xor(sv, 2);
        sv += __shfl_xor(sv, 4); sv += __shfl_xor(sv, 8);
        float inv = 1.f / fmaxf(sqrtf(sv), 1e-12f);
        vx.x *= inv; vx.y *= inv; vx.z *= inv; vx.w *= inv;
        *(float4*)&s.a.V[jc][c] = vx;
    }
    __syncthreads();

    int i_loc = t & 31;
    int jgrp  = t >> 5;
    int i_glob = i0 + i_loc;
    float q[16];
    #pragma unroll
    for (int c = 0; c < 16; ++c) q[c] = s.a.Q[i_loc][c];

    #pragma unroll
    for (int jj = 0; jj < 8; ++jj) {
        int jc = jgrp * 8 + jj;
        int j = j0 + jc;
        int d = i_glob - j;
        float sim = 0.f;
        #pragma unroll
        for (int c4 = 0; c4 < 4; ++c4) {
            float4 kk4 = *(const float4*)&s.a.K[jc][c4 * 4];
            sim += q[c4*4+0]*kk4.x + q[c4*4+1]*kk4.y
                 + q[c4*4+2]*kk4.z + q[c4*4+3]*kk4.w;
        }
        float a = fmaxf(1.f - r * (1.f - sim), 0.f);
        int dc = min(max(d, 0), dmax);
        bool valid = (d >= 0) && (d <= dmax);
        s.a.att[i_loc][jc] = valid ? a * a * s.a.soft[dc] : 0.f;
    }
    __syncthreads();

    int wv = t >> 6, ihalf = (t >> 5) & 1, dvp = t & 31;
    int ib = wv * 8 + ihalf * 4;
    float acc[4][2] = {};

    #pragma unroll
    for (int g4 = 0; g4 < 16; ++g4) {
        int jc0 = g4 * 4;
        float4 am[4];
        #pragma unroll
        for (int m = 0; m < 4; ++m)
            am[m] = *(const float4*)&s.a.att[ib + m][jc0];
        float2 v0 = *(const float2*)&s.a.V[jc0 + 0][dvp * 2];
        float2 v1 = *(const float2*)&s.a.V[jc0 + 1][dvp * 2];
        float2 v2 = *(const float2*)&s.a.V[jc0 + 2][dvp * 2];
        float2 v3 = *(const float2*)&s.a.V[jc0 + 3][dvp * 2];
        #pragma unroll
        for (int m = 0; m < 4; ++m) {
            acc[m][0] += am[m].x * v0.x + am[m].y * v1.x
                       + am[m].z * v2.x + am[m].w * v3.x;
            acc[m][1] += am[m].x * v0.y + am[m].y * v1.y
                       + am[m].z * v2.y + am[m].w * v3.y;
        }
    }

    if (nch == 1) {
        float hs = expf(log_hscale[h]);
        #pragma unroll
        for (int m = 0; m < 4; ++m) {
            float ss = acc[m][0]*acc[m][0] + acc[m][1]*acc[m][1];
            #pragma unroll
            for (int off = 16; off; off >>= 1) ss += __shfl_xor(ss, off);
            float norm = sqrtf(ss);
            float scale = tanhf(norm) / fmaxf(norm, 1e-12f);
            int i = i0 + ib + m;
            float2 g2 = *(const float2*)(qg + (size_t)i * QGN + h * QGW + DKQ + dvp * 2);
            float gate0 = tanhf(g2.x / (1.f + expf(-g2.x)));
            float gate1 = tanhf(g2.y / (1.f + expf(-g2.y)));
            __hip_bfloat16 ob[2] = { __float2bfloat16(acc[m][0] * scale * gate0 * hs),
                                     __float2bfloat16(acc[m][1] * scale * gate1 * hs) };
            *(ushort2*)(Yb + (size_t)i * HD + h * DVH + dvp * 2) = *(const ushort2*)ob;
        }
    } else {
        #pragma unroll
        for (int m = 0; m < 4; ++m) {
            int i = i0 + ib + m;
            float2 st = make_float2(acc[m][0], acc[m][1]);
            *(float2*)(Ypart + ((size_t)slot * N_TOK + i) * HD + h * DVH + dvp * 2) = st;
        }
    }
}

// ---------------------------------------------------------------------------
// epilogue unit: 4 waves x one (h,i) each; unit in [0, 3072) covers h {5,6,7}
// ---------------------------------------------------------------------------
__device__ __forceinline__ void dev_epi_unit(int unit, int t,
    const float* __restrict__ Ypart, const float* __restrict__ qg,
    const float* __restrict__ log_window, const float* __restrict__ log_hscale,
    __hip_bfloat16* __restrict__ Y)
{
    int wv = t >> 6, lane = t & 63;
    int gid = 5 * N_TOK + unit * 4 + wv;
    int h = gid >> 12;
    int i = gid & (N_TOK - 1);

    float w  = expf(log_window[h]) + 1.f;
    int dmax = (int)ceilf(w) - 1;
    int i0 = i & ~(TI - 1);
    int jstart = i0 - dmax; if (jstart < 0) jstart = 0;
    int nch = (i0 + TI - jstart + DC - 1) / DC;
    if (nch < 2) return;

    float hs = expf(log_hscale[h]);
    size_t base = (size_t)i * HD + h * DVH + lane;
    float a = 0.f;
    for (int c = 0; c < nch; ++c)
        a += Ypart[(size_t)c * N_TOK * HD + base];

    float g = qg[(size_t)i * QGN + h * QGW + DKQ + lane];
    float gate = tanhf(g / (1.f + expf(-g)));

    float ss = a * a;
    #pragma unroll
    for (int off = 32; off; off >>= 1) ss += __shfl_xor(ss, off);
    float norm = sqrtf(ss);
    float scale = tanhf(norm) / fmaxf(norm, 1e-12f);

    float o = a * scale * gate * hs;
    Y[(size_t)i * HD + h * DVH + lane] = __float2bfloat16(o);
}

// ===========================================================================
// Cooperative mega-kernel: all 5 phases, grid.sync() between them.
// ===========================================================================
__global__ __launch_bounds__(256, 3) void mega_kernel(
    const float* tokens, const float* w_qg, const float* w_kv, const float* w_out,
    const float* log_window, const float* log_r, const float* log_hscale,
    __hip_bfloat16* tokB, __hip_bfloat16* wqgT, __hip_bfloat16* wkvT,
    __hip_bfloat16* woutT, float* qg, float* kv, float* Ypart,
    __hip_bfloat16* Yb, float* out)
{
    cg::grid_group grid = cg::this_grid();
    __shared__ Smem s;
    int t = threadIdx.x;
    int b = blockIdx.x;

    // P0a: tokens fp32 -> bf16 (flat)
    for (size_t i4 = (size_t)b * 256 + t; i4 < (size_t)N_TOK * D_MODEL / 4;
         i4 += (size_t)NBLK * 256) {
        float4 v = ((const float4*)tokens)[i4];
        __hip_bfloat16 o[4] = { __float2bfloat16(v.x), __float2bfloat16(v.y),
                                __float2bfloat16(v.z), __float2bfloat16(v.w) };
        ((ushort4*)tokB)[i4] = *(const ushort4*)o;
    }
    // P0b: weight transposes
    for (int u = b; u < 1792; u += NBLK)
        dev_pack_w(s, u, w_qg, w_kv, w_out, wqgT, wkvT, woutT, t);
    grid.sync();

    // P1: projection GEMM (640 tiles, one per block)
    for (int u = b; u < 640; u += NBLK)
        dev_gemm1_unit(s, u, tokB, wqgT, wkvT, qg, kv, t);
    grid.sync();

    // P2: attention chunks (5120 units)
    for (int u = b; u < NHEAD * 128 * NCH_MAX; u += NBLK)
        dev_attn_unit(s, u, qg, kv, log_window, log_r, log_hscale, Ypart, Yb, t);
    grid.sync();

    // P3: epilogue for multi-chunk rows (3072 units: 3 heads x 4096 / 4)
    for (int u = b; u < EPI_UNITS; u += NBLK)
        dev_epi_unit(u, t, Ypart, qg, log_window, log_hscale, Yb);
    grid.sync();

    // P4: output GEMM (512 tiles)
    for (int u = b; u < 512; u += NBLK)
        dev_gemm2_unit(s, u, Yb, woutT, out, t);
}

// ===========================================================================
// Fallback wrappers (R7-equivalent 5-kernel path)
// ===========================================================================
__global__ __launch_bounds__(256) void pack_kernel(
    const float* tokens, const float* w_qg, const float* w_kv, const float* w_out,
    __hip_bfloat16* tokB, __hip_bfloat16* wqgT, __hip_bfloat16* wkvT,
    __hip_bfloat16* woutT)
{
    __shared__ Smem s;
    int b = blockIdx.x, t = threadIdx.x;
    if (b < 4096) {
        int i = (b * 256 + t) * 4;
        float4 v = *(const float4*)(tokens + i);
        __hip_bfloat16 o[4] = { __float2bfloat16(v.x), __float2bfloat16(v.y),
                                __float2bfloat16(v.z), __float2bfloat16(v.w) };
        *(ushort4*)(tokB + i) = *(const ushort4*)o;
        return;
    }
    dev_pack_w(s, b - 4096, w_qg, w_kv, w_out, wqgT, wkvT, woutT, t);
}

__global__ __launch_bounds__(256) void gemm1_kernel(
    const __hip_bfloat16* tokB, const __hip_bfloat16* wqgT,
    const __hip_bfloat16* wkvT, float* qg, float* kv)
{
    __shared__ Smem s;
    dev_gemm1_unit(s, blockIdx.y * 20 + blockIdx.x, tokB, wqgT, wkvT, qg, kv,
                   threadIdx.x);
}

__global__ __launch_bounds__(256) void attn_kernel(
    const float* qg, const float* kv, const float* log_window,
    const float* log_r, const float* log_hscale, float* Ypart,
    __hip_bfloat16* Yb)
{
    __shared__ Smem s;
    dev_attn_unit(s, blockIdx.x, qg, kv, log_window, log_r, log_hscale,
                  Ypart, Yb, threadIdx.x);
}

__global__ __launch_bounds__(256) void epi_kernel(
    const float* Ypart, const float* qg, const float* log_window,
    const float* log_hscale, __hip_bfloat16* Yb)
{
    dev_epi_unit(blockIdx.x, threadIdx.x, Ypart, qg, log_window, log_hscale, Yb);
}

__global__ __launch_bounds__(256) void gemm2_kernel(
    const __hip_bfloat16* Yb, const __hip_bfloat16* woutT, float* out)
{
    __shared__ Smem s;
    dev_gemm2_unit(s, blockIdx.y * 16 + blockIdx.x, Yb, woutT, out, threadIdx.x);
}

// ---------------------------------------------------------------------------
extern "C" void kernel_launch(void* const* d_in, const int* in_sizes, int n_in,
                              void* d_out, int out_size, void* d_ws, size_t ws_size,
                              hipStream_t stream)
{
    const float* tokens     = (const float*)d_in[0];
    const float* w_qg       = (const float*)d_in[1];
    const float* w_kv       = (const float*)d_in[2];
    const float* w_out      = (const float*)d_in[3];
    const float* log_window = (const float*)d_in[4];
    const float* log_r      = (const float*)d_in[5];
    const float* log_hscale = (const float*)d_in[6];
    float* out = (float*)d_out;

    char* ws = (char*)d_ws;
    float* qg = (float*)ws;            ws += (size_t)N_TOK * QGN * 4;
    float* kv = (float*)ws;            ws += (size_t)N_TOK * QGN * 4;
    __hip_bfloat16* tokB  = (__hip_bfloat16*)ws; ws += (size_t)N_TOK * D_MODEL * 2;
    __hip_bfloat16* wqgT  = (__hip_bfloat16*)ws; ws += (size_t)QGN * D_MODEL * 2;
    __hip_bfloat16* wkvT  = (__hip_bfloat16*)ws; ws += (size_t)QGN * D_MODEL * 2;
    __hip_bfloat16* woutT = (__hip_bfloat16*)ws; ws += (size_t)D_MODEL * HD * 2;
    __hip_bfloat16* Yb    = (__hip_bfloat16*)ws; ws += (size_t)N_TOK * HD * 2;
    float* Ypart = (float*)ws;         ws += (size_t)NCH_MAX * N_TOK * HD * 4;

    void* args[] = { (void*)&tokens, (void*)&w_qg, (void*)&w_kv, (void*)&w_out,
                     (void*)&log_window, (void*)&log_r, (void*)&log_hscale,
                     (void*)&tokB, (void*)&wqgT, (void*)&wkvT, (void*)&woutT,
                     (void*)&qg, (void*)&kv, (void*)&Ypart, (void*)&Yb,
                     (void*)&out };
    hipError_t e = hipLaunchCooperativeKernel((const void*)mega_kernel,
                                              dim3(NBLK), dim3(256),
                                              args, 0, stream);
    if (e != hipSuccess) {
        (void)hipGetLastError();   // clear, take the 5-kernel path
        pack_kernel<<<5888, 256, 0, stream>>>(tokens, w_qg, w_kv, w_out,
                                              tokB, wqgT, wkvT, woutT);
        gemm1_kernel<<<dim3(20, 32), 256, 0, stream>>>(tokB, wqgT, wkvT, qg, kv);
        attn_kernel<<<NHEAD * 128 * NCH_MAX, 256, 0, stream>>>(
            qg, kv, log_window, log_r, log_hscale, Ypart, Yb);
        epi_kernel<<<EPI_UNITS, 256, 0, stream>>>(Ypart, qg, log_window,
                                                  log_hscale, Yb);
        gemm2_kernel<<<dim3(16, 32), 256, 0, stream>>>(Yb, woutT, out);
    }
}

// Round 11
// 81.997 us; speedup vs baseline: 6.1677x; 6.1677x over previous
//
#include <hip/hip_runtime.h>
#include <hip/hip_bf16.h>
#include <math.h>

#define N_TOK 4096
#define D_MODEL 1024
#define NHEAD 8
#define DKQ 16
#define DVH 64
#define QGW 80   // DK+DV columns per head
#define QGN 640  // H * 80
#define HD  512  // H * DV
#define TI  32   // attention: i-rows per tile
#define DC  64   // attention: j-chunk width
#define NCH_MAX 5
#define EPI_UNITS (3 * N_TOK / 4)   // h in {5,6,7}, 4 rows per unit

typedef __attribute__((ext_vector_type(8))) short short8;
typedef __attribute__((ext_vector_type(4))) float f32x4;

#define GLOAD_LDS16(gp, lp) \
  __builtin_amdgcn_global_load_lds((const __attribute__((address_space(1))) void*)(gp), \
                                   (__attribute__((address_space(3))) void*)(lp), 16, 0, 0)

// ---------------------------------------------------------------------------
// pack: tokens fp32->bf16 cast + 3 weight transpose+casts, by block range.
// ---------------------------------------------------------------------------
__global__ __launch_bounds__(256) void pack_kernel(
    const float* __restrict__ tokens, const float* __restrict__ w_qg,
    const float* __restrict__ w_kv, const float* __restrict__ w_out,
    __hip_bfloat16* __restrict__ tokB, __hip_bfloat16* __restrict__ wqgT,
    __hip_bfloat16* __restrict__ wkvT, __hip_bfloat16* __restrict__ woutT)
{
    __shared__ float tile[32][33];
    int b = blockIdx.x;
    int t = threadIdx.x;

    if (b < 4096) {                       // tokens cast
        int i = (b * 256 + t) * 4;
        float4 v = *(const float4*)(tokens + i);
        __hip_bfloat16 o[4] = { __float2bfloat16(v.x), __float2bfloat16(v.y),
                                __float2bfloat16(v.z), __float2bfloat16(v.w) };
        *(ushort4*)(tokB + i) = *(const ushort4*)o;
        return;
    }

    const float* in; __hip_bfloat16* outp; int R, C, tb;
    b -= 4096;
    if (b < 640)       { in = w_qg;  outp = wqgT;  R = 1024; C = 640;  tb = b; }
    else if (b < 1280) { in = w_kv;  outp = wkvT;  R = 1024; C = 640;  tb = b - 640; }
    else               { in = w_out; outp = woutT; R = 512;  C = 1024; tb = b - 1280; }
    int ctiles = C / 32;
    int bx = (tb % ctiles) * 32;
    int by = (tb / ctiles) * 32;
    int tx = t & 31, ty = t >> 5;

    #pragma unroll
    for (int j = 0; j < 32; j += 8)
        tile[j + ty][tx] = in[(size_t)(by + j + ty) * C + bx + tx];
    __syncthreads();
    #pragma unroll
    for (int j = 0; j < 32; j += 8)
        outp[(size_t)(bx + j + ty) * R + by + tx] =
            __float2bfloat16(tile[tx][j + ty]);
}

// ---------------------------------------------------------------------------
// bf16 MFMA GEMM, 128x64 tile, TWO BK=32 sub-tiles per barrier pair (24KB LDS,
// halves barrier count vs R7). C = A * Bt^T. Dual-B via blockIdx.x.
// K-accumulation order identical to R7 -> bit-identical output.
// ---------------------------------------------------------------------------
__global__ __launch_bounds__(256) void gemm_mfma(
    const __hip_bfloat16* __restrict__ A,
    const __hip_bfloat16* __restrict__ Bt0, float* __restrict__ C0,
    const __hip_bfloat16* __restrict__ Bt1, float* __restrict__ C1,
    int Nb, int K, int ntiles_n)
{
    __shared__ __hip_bfloat16 As[2][128 * 32];   // 16 KB
    __shared__ __hip_bfloat16 Bs[2][64 * 32];    //  8 KB

    int t = threadIdx.x;
    int l = t & 63;
    int w = t >> 6;
    int wr = w >> 1, wc = w & 1;

    int bnt = blockIdx.x;
    const __hip_bfloat16* Bt = Bt0;
    float* C = C0;
    if (bnt >= ntiles_n) { Bt = Bt1; C = C1; bnt -= ntiles_n; }
    int bm = blockIdx.y * 128;
    int bn = bnt * 64;

    int srow = t >> 2;
    int skc  = (t & 3) * 8;
    const __hip_bfloat16* ga0 = A + (size_t)(bm + srow) * K + skc;
    const __hip_bfloat16* ga1 = A + (size_t)(bm + 64 + srow) * K + skc;
    const __hip_bfloat16* gb  = Bt + (size_t)(bn + srow) * K + skc;
    int ldst = (t & ~63) * 8;           // wave-uniform LDS base (elems)

    f32x4 acc[4][2] = {};

    int aro = (wr * 64 + (l & 15)) * 32 + (l >> 4) * 8;
    int bro = (wc * 32 + (l & 15)) * 32 + (l >> 4) * 8;

    for (int k0 = 0; k0 < K; k0 += 64) {
        GLOAD_LDS16(ga0 + k0,      &As[0][ldst]);
        GLOAD_LDS16(ga1 + k0,      &As[0][2048 + ldst]);
        GLOAD_LDS16(gb  + k0,      &Bs[0][ldst]);
        GLOAD_LDS16(ga0 + k0 + 32, &As[1][ldst]);
        GLOAD_LDS16(ga1 + k0 + 32, &As[1][2048 + ldst]);
        GLOAD_LDS16(gb  + k0 + 32, &Bs[1][ldst]);
        __syncthreads();

        #pragma unroll
        for (int kk = 0; kk < 2; ++kk) {
            short8 af[4], bf[2];
            #pragma unroll
            for (int m = 0; m < 4; ++m)
                af[m] = *(const short8*)&As[kk][aro + m * 16 * 32];
            #pragma unroll
            for (int n = 0; n < 2; ++n)
                bf[n] = *(const short8*)&Bs[kk][bro + n * 16 * 32];

            #pragma unroll
            for (int m = 0; m < 4; ++m)
                #pragma unroll
                for (int n = 0; n < 2; ++n)
                    acc[m][n] = __builtin_amdgcn_mfma_f32_16x16x32_bf16(
                                    af[m], bf[n], acc[m][n], 0, 0, 0);
        }
        __syncthreads();
    }

    int crow = bm + wr * 64 + (l >> 4) * 4;
    int ccol = bn + wc * 32 + (l & 15);
    #pragma unroll
    for (int m = 0; m < 4; ++m)
        #pragma unroll
        for (int n = 0; n < 2; ++n)
            #pragma unroll
            for (int j = 0; j < 4; ++j)
                C[(size_t)(crow + m * 16 + j) * Nb + ccol + n * 16] = acc[m][n][j];
}

// ---------------------------------------------------------------------------
// Chunk-parallel banded attention, fused normalization; fused epilogue when
// nch==1, else partial to Ypart. (R7-proven)
// ---------------------------------------------------------------------------
__global__ __launch_bounds__(256) void attn_chunk_kernel(
    const float* __restrict__ qg, const float* __restrict__ kv,
    const float* __restrict__ log_window, const float* __restrict__ log_r,
    const float* __restrict__ log_hscale,
    float* __restrict__ Ypart, __hip_bfloat16* __restrict__ Yb)
{
    int bid = blockIdx.x;                 // h*(128*NCH_MAX) + tile*NCH_MAX + slot
    int h    = bid / (128 * NCH_MAX);
    int rem  = bid - h * (128 * NCH_MAX);
    int tile = rem / NCH_MAX;
    int slot = rem - tile * NCH_MAX;
    int i0 = tile * TI;
    int t = threadIdx.x;

    float w = expf(log_window[h]) + 1.f;
    float r = expf(log_r[h]) + 1.f;
    int dmax = (int)ceilf(w) - 1;
    int jstart = i0 - dmax; if (jstart < 0) jstart = 0;
    int nch = (i0 + TI - jstart + DC - 1) / DC;
    if (slot >= nch) return;
    int j0 = jstart + slot * DC;

    __shared__ float Q_lds[TI][16];
    __shared__ float K_lds[DC][16];
    __shared__ float V_lds[DC][DVH];
    __shared__ float att_lds[TI][68];
    __shared__ float soft_lds[288];

    const float PI = 3.14159265358979f;
    for (int d = t; d <= dmax; d += 256)
        soft_lds[d] = 0.5f * (cosf(PI * (float)d / w) + 1.f);

    if (t < TI * 4) {
        int iq = t >> 2, c = (t & 3) * 4;
        float4 qv = *(const float4*)(qg + (size_t)(i0 + iq) * QGN + h * QGW + c);
        float s = qv.x*qv.x + qv.y*qv.y + qv.z*qv.z + qv.w*qv.w;
        s += __shfl_xor(s, 1); s += __shfl_xor(s, 2);
        float inv = 1.f / fmaxf(sqrtf(s), 1e-12f);
        qv.x *= inv; qv.y *= inv; qv.z *= inv; qv.w *= inv;
        *(float4*)&Q_lds[iq][c] = qv;
    }
    {
        int jr = t >> 2, c = (t & 3) * 4;
        int j = j0 + jr;
        float4 kx = make_float4(0.f, 0.f, 0.f, 0.f);
        if (j < N_TOK)
            kx = *(const float4*)(kv + (size_t)j * QGN + h * QGW + c);
        float s = kx.x*kx.x + kx.y*kx.y + kx.z*kx.z + kx.w*kx.w;
        s += __shfl_xor(s, 1); s += __shfl_xor(s, 2);
        float inv = 1.f / fmaxf(sqrtf(s), 1e-12f);
        kx.x *= inv; kx.y *= inv; kx.z *= inv; kx.w *= inv;
        *(float4*)&K_lds[jr][c] = kx;
    }
    #pragma unroll
    for (int kk = 0; kk < 4; ++kk) {
        int f = t + kk * 256;
        int jc = f >> 4, c = (f & 15) * 4;
        int j = j0 + jc;
        float4 vx = make_float4(0.f, 0.f, 0.f, 0.f);
        if (j < N_TOK)
            vx = *(const float4*)(kv + (size_t)j * QGN + h * QGW + DKQ + c);
        float s = vx.x*vx.x + vx.y*vx.y + vx.z*vx.z + vx.w*vx.w;
        s += __shfl_xor(s, 1); s += __shfl_xor(s, 2);
        s += __shfl_xor(s, 4); s += __shfl_xor(s, 8);
        float inv = 1.f / fmaxf(sqrtf(s), 1e-12f);
        vx.x *= inv; vx.y *= inv; vx.z *= inv; vx.w *= inv;
        *(float4*)&V_lds[jc][c] = vx;
    }
    __syncthreads();

    int i_loc = t & 31;
    int jgrp  = t >> 5;
    int i_glob = i0 + i_loc;
    float q[16];
    #pragma unroll
    for (int c = 0; c < 16; ++c) q[c] = Q_lds[i_loc][c];

    #pragma unroll
    for (int jj = 0; jj < 8; ++jj) {
        int jc = jgrp * 8 + jj;
        int j = j0 + jc;
        int d = i_glob - j;
        float sim = 0.f;
        #pragma unroll
        for (int c4 = 0; c4 < 4; ++c4) {
            float4 kk4 = *(const float4*)&K_lds[jc][c4 * 4];
            sim += q[c4*4+0]*kk4.x + q[c4*4+1]*kk4.y
                 + q[c4*4+2]*kk4.z + q[c4*4+3]*kk4.w;
        }
        float a = fmaxf(1.f - r * (1.f - sim), 0.f);
        int dc = min(max(d, 0), dmax);
        bool valid = (d >= 0) && (d <= dmax);
        att_lds[i_loc][jc] = valid ? a * a * soft_lds[dc] : 0.f;
    }
    __syncthreads();

    int wv = t >> 6, ihalf = (t >> 5) & 1, dvp = t & 31;
    int ib = wv * 8 + ihalf * 4;
    float acc[4][2] = {};

    #pragma unroll
    for (int g4 = 0; g4 < 16; ++g4) {
        int jc0 = g4 * 4;
        float4 am[4];
        #pragma unroll
        for (int m = 0; m < 4; ++m)
            am[m] = *(const float4*)&att_lds[ib + m][jc0];
        float2 v0 = *(const float2*)&V_lds[jc0 + 0][dvp * 2];
        float2 v1 = *(const float2*)&V_lds[jc0 + 1][dvp * 2];
        float2 v2 = *(const float2*)&V_lds[jc0 + 2][dvp * 2];
        float2 v3 = *(const float2*)&V_lds[jc0 + 3][dvp * 2];
        #pragma unroll
        for (int m = 0; m < 4; ++m) {
            acc[m][0] += am[m].x * v0.x + am[m].y * v1.x
                       + am[m].z * v2.x + am[m].w * v3.x;
            acc[m][1] += am[m].x * v0.y + am[m].y * v1.y
                       + am[m].z * v2.y + am[m].w * v3.y;
        }
    }

    if (nch == 1) {
        float hs = expf(log_hscale[h]);
        #pragma unroll
        for (int m = 0; m < 4; ++m) {
            float ss = acc[m][0]*acc[m][0] + acc[m][1]*acc[m][1];
            #pragma unroll
            for (int off = 16; off; off >>= 1) ss += __shfl_xor(ss, off);
            float norm = sqrtf(ss);
            float scale = tanhf(norm) / fmaxf(norm, 1e-12f);
            int i = i0 + ib + m;
            float2 g2 = *(const float2*)(qg + (size_t)i * QGN + h * QGW + DKQ + dvp * 2);
            float gate0 = tanhf(g2.x / (1.f + expf(-g2.x)));
            float gate1 = tanhf(g2.y / (1.f + expf(-g2.y)));
            __hip_bfloat16 ob[2] = { __float2bfloat16(acc[m][0] * scale * gate0 * hs),
                                     __float2bfloat16(acc[m][1] * scale * gate1 * hs) };
            *(ushort2*)(Yb + (size_t)i * HD + h * DVH + dvp * 2) = *(const ushort2*)ob;
        }
    } else {
        #pragma unroll
        for (int m = 0; m < 4; ++m) {
            int i = i0 + ib + m;
            float2 st = make_float2(acc[m][0], acc[m][1]);
            *(float2*)(Ypart + ((size_t)slot * N_TOK + i) * HD + h * DVH + dvp * 2) = st;
        }
    }
}

// ---------------------------------------------------------------------------
// Epilogue for multi-chunk rows only (h in {5,6,7}). One wave per (h, i).
// ---------------------------------------------------------------------------
__global__ __launch_bounds__(256) void attn_epilogue_kernel(
    const float* __restrict__ Ypart, const float* __restrict__ qg,
    const float* __restrict__ log_window, const float* __restrict__ log_hscale,
    __hip_bfloat16* __restrict__ Y)
{
    int wv = threadIdx.x >> 6, lane = threadIdx.x & 63;
    int gid = 5 * N_TOK + blockIdx.x * 4 + wv;   // h*N_TOK + i
    int h = gid >> 12;
    int i = gid & (N_TOK - 1);

    float w  = expf(log_window[h]) + 1.f;
    int dmax = (int)ceilf(w) - 1;
    int i0 = i & ~(TI - 1);
    int jstart = i0 - dmax; if (jstart < 0) jstart = 0;
    int nch = (i0 + TI - jstart + DC - 1) / DC;
    if (nch < 2) return;

    float hs = expf(log_hscale[h]);
    size_t base = (size_t)i * HD + h * DVH + lane;
    float a = 0.f;
    for (int c = 0; c < nch; ++c)
        a += Ypart[(size_t)c * N_TOK * HD + base];

    float g = qg[(size_t)i * QGN + h * QGW + DKQ + lane];
    float gate = tanhf(g / (1.f + expf(-g)));

    float ss = a * a;
    #pragma unroll
    for (int off = 32; off; off >>= 1) ss += __shfl_xor(ss, off);
    float norm = sqrtf(ss);
    float scale = tanhf(norm) / fmaxf(norm, 1e-12f);

    float o = a * scale * gate * hs;
    Y[(size_t)i * HD + h * DVH + lane] = __float2bfloat16(o);
}

// ---------------------------------------------------------------------------
extern "C" void kernel_launch(void* const* d_in, const int* in_sizes, int n_in,
                              void* d_out, int out_size, void* d_ws, size_t ws_size,
                              hipStream_t stream)
{
    const float* tokens     = (const float*)d_in[0];
    const float* w_qg       = (const float*)d_in[1];
    const float* w_kv       = (const float*)d_in[2];
    const float* w_out      = (const float*)d_in[3];
    const float* log_window = (const float*)d_in[4];
    const float* log_r      = (const float*)d_in[5];
    const float* log_hscale = (const float*)d_in[6];
    float* out = (float*)d_out;

    char* ws = (char*)d_ws;
    float* qg = (float*)ws;            ws += (size_t)N_TOK * QGN * 4;
    float* kv = (float*)ws;            ws += (size_t)N_TOK * QGN * 4;
    __hip_bfloat16* tokB  = (__hip_bfloat16*)ws; ws += (size_t)N_TOK * D_MODEL * 2;
    __hip_bfloat16* wqgT  = (__hip_bfloat16*)ws; ws += (size_t)QGN * D_MODEL * 2;
    __hip_bfloat16* wkvT  = (__hip_bfloat16*)ws; ws += (size_t)QGN * D_MODEL * 2;
    __hip_bfloat16* woutT = (__hip_bfloat16*)ws; ws += (size_t)D_MODEL * HD * 2;
    __hip_bfloat16* Yb    = (__hip_bfloat16*)ws; ws += (size_t)N_TOK * HD * 2;
    float* Ypart = (float*)ws;         ws += (size_t)NCH_MAX * N_TOK * HD * 4;

    // 0) pack: tokens cast + weight transposes
    pack_kernel<<<5888, 256, 0, stream>>>(tokens, w_qg, w_kv, w_out,
                                          tokB, wqgT, wkvT, woutT);
    // 1) qg / kv projection (dual-B, BN=64 -> 640 blocks)
    {
        dim3 grid(2 * (QGN / 64), N_TOK / 128);
        gemm_mfma<<<grid, 256, 0, stream>>>(tokB, wqgT, qg, wkvT, kv,
                                            QGN, D_MODEL, QGN / 64);
    }
    // 2) chunk-parallel attention (fused norm; fused epilogue when nch==1)
    attn_chunk_kernel<<<NHEAD * (N_TOK / TI) * NCH_MAX, 256, 0, stream>>>(
        qg, kv, log_window, log_r, log_hscale, Ypart, Yb);
    // 3) epilogue for multi-chunk rows
    attn_epilogue_kernel<<<EPI_UNITS, 256, 0, stream>>>(
        Ypart, qg, log_window, log_hscale, Yb);
    // 4) out = Y @ w_out
    {
        dim3 grid(D_MODEL / 64, N_TOK / 128);
        gemm_mfma<<<grid, 256, 0, stream>>>(Yb, woutT, out, woutT, out,
                                            D_MODEL, HD, D_MODEL / 64);
    }
}

// Round 12
// 80.677 us; speedup vs baseline: 6.2686x; 1.0164x over previous
//
#include <hip/hip_runtime.h>
#include <hip/hip_bf16.h>
#include <math.h>

#define N_TOK 4096
#define D_MODEL 1024
#define NHEAD 8
#define DKQ 16
#define DVH 64
#define QGW 80   // DK+DV columns per head
#define QGN 640  // H * 80
#define HD  512  // H * DV
#define TI  32   // attention: i-rows per tile
#define DC  64   // attention: j-chunk width
#define NCH_MAX 5
#define EPI_UNITS (3 * N_TOK / 4)   // h in {5,6,7}, 4 rows per unit

typedef __attribute__((ext_vector_type(8))) short short8;
typedef __attribute__((ext_vector_type(4))) float f32x4;

#define GLOAD_LDS16(gp, lp) \
  __builtin_amdgcn_global_load_lds((const __attribute__((address_space(1))) void*)(gp), \
                                   (__attribute__((address_space(3))) void*)(lp), 16, 0, 0)

// ---------------------------------------------------------------------------
// pack: tokens fp32->bf16 cast + 3 weight transpose+casts, by block range.
// ---------------------------------------------------------------------------
__global__ __launch_bounds__(256) void pack_kernel(
    const float* __restrict__ tokens, const float* __restrict__ w_qg,
    const float* __restrict__ w_kv, const float* __restrict__ w_out,
    __hip_bfloat16* __restrict__ tokB, __hip_bfloat16* __restrict__ wqgT,
    __hip_bfloat16* __restrict__ wkvT, __hip_bfloat16* __restrict__ woutT)
{
    __shared__ float tile[32][33];
    int b = blockIdx.x;
    int t = threadIdx.x;

    if (b < 4096) {                       // tokens cast
        int i = (b * 256 + t) * 4;
        float4 v = *(const float4*)(tokens + i);
        __hip_bfloat16 o[4] = { __float2bfloat16(v.x), __float2bfloat16(v.y),
                                __float2bfloat16(v.z), __float2bfloat16(v.w) };
        *(ushort4*)(tokB + i) = *(const ushort4*)o;
        return;
    }

    const float* in; __hip_bfloat16* outp; int R, C, tb;
    b -= 4096;
    if (b < 640)       { in = w_qg;  outp = wqgT;  R = 1024; C = 640;  tb = b; }
    else if (b < 1280) { in = w_kv;  outp = wkvT;  R = 1024; C = 640;  tb = b - 640; }
    else               { in = w_out; outp = woutT; R = 512;  C = 1024; tb = b - 1280; }
    int ctiles = C / 32;
    int bx = (tb % ctiles) * 32;
    int by = (tb / ctiles) * 32;
    int tx = t & 31, ty = t >> 5;

    #pragma unroll
    for (int j = 0; j < 32; j += 8)
        tile[j + ty][tx] = in[(size_t)(by + j + ty) * C + bx + tx];
    __syncthreads();
    #pragma unroll
    for (int j = 0; j < 32; j += 8)
        outp[(size_t)(bx + j + ty) * R + by + tx] =
            __float2bfloat16(tile[tx][j + ty]);
}

// ---------------------------------------------------------------------------
// bf16 MFMA GEMM, 128x64 tile, BK=64 steps, DOUBLE-BUFFERED (48KB LDS):
// stage(next) -> compute(cur) -> barrier. One barrier per K-step; global-load
// latency hides under MFMA. K-accumulation order identical -> bit-identical.
// ---------------------------------------------------------------------------
__global__ __launch_bounds__(256) void gemm_mfma(
    const __hip_bfloat16* __restrict__ A,
    const __hip_bfloat16* __restrict__ Bt0, float* __restrict__ C0,
    const __hip_bfloat16* __restrict__ Bt1, float* __restrict__ C1,
    int Nb, int K, int ntiles_n)
{
    __shared__ __hip_bfloat16 As[2][2][128 * 32];   // 32 KB
    __shared__ __hip_bfloat16 Bs[2][2][64 * 32];    // 16 KB

    int t = threadIdx.x;
    int l = t & 63;
    int w = t >> 6;
    int wr = w >> 1, wc = w & 1;

    int bnt = blockIdx.x;
    const __hip_bfloat16* Bt = Bt0;
    float* C = C0;
    if (bnt >= ntiles_n) { Bt = Bt1; C = C1; bnt -= ntiles_n; }
    int bm = blockIdx.y * 128;
    int bn = bnt * 64;

    int srow = t >> 2;
    int skc  = (t & 3) * 8;
    const __hip_bfloat16* ga0 = A + (size_t)(bm + srow) * K + skc;
    const __hip_bfloat16* ga1 = A + (size_t)(bm + 64 + srow) * K + skc;
    const __hip_bfloat16* gb  = Bt + (size_t)(bn + srow) * K + skc;
    int ldst = (t & ~63) * 8;           // wave-uniform LDS base (elems)

#define STAGE(buf, k0) do { \
    GLOAD_LDS16(ga0 + (k0),      &As[buf][0][ldst]); \
    GLOAD_LDS16(ga1 + (k0),      &As[buf][0][2048 + ldst]); \
    GLOAD_LDS16(gb  + (k0),      &Bs[buf][0][ldst]); \
    GLOAD_LDS16(ga0 + (k0) + 32, &As[buf][1][ldst]); \
    GLOAD_LDS16(ga1 + (k0) + 32, &As[buf][1][2048 + ldst]); \
    GLOAD_LDS16(gb  + (k0) + 32, &Bs[buf][1][ldst]); } while (0)

    f32x4 acc[4][2] = {};

    int aro = (wr * 64 + (l & 15)) * 32 + (l >> 4) * 8;
    int bro = (wc * 32 + (l & 15)) * 32 + (l >> 4) * 8;

    int nk = K >> 6;                    // K / 64
    STAGE(0, 0);                        // prologue
    __syncthreads();

    int cur = 0;
    for (int it = 0; it < nk; ++it) {
        if (it + 1 < nk) STAGE(cur ^ 1, (it + 1) << 6);   // prefetch next

        #pragma unroll
        for (int kk = 0; kk < 2; ++kk) {
            short8 af[4], bf[2];
            #pragma unroll
            for (int m = 0; m < 4; ++m)
                af[m] = *(const short8*)&As[cur][kk][aro + m * 16 * 32];
            #pragma unroll
            for (int n = 0; n < 2; ++n)
                bf[n] = *(const short8*)&Bs[cur][kk][bro + n * 16 * 32];

            #pragma unroll
            for (int m = 0; m < 4; ++m)
                #pragma unroll
                for (int n = 0; n < 2; ++n)
                    acc[m][n] = __builtin_amdgcn_mfma_f32_16x16x32_bf16(
                                    af[m], bf[n], acc[m][n], 0, 0, 0);
        }
        __syncthreads();                // drains prefetch; next buf ready
        cur ^= 1;
    }
#undef STAGE

    int crow = bm + wr * 64 + (l >> 4) * 4;
    int ccol = bn + wc * 32 + (l & 15);
    #pragma unroll
    for (int m = 0; m < 4; ++m)
        #pragma unroll
        for (int n = 0; n < 2; ++n)
            #pragma unroll
            for (int j = 0; j < 4; ++j)
                C[(size_t)(crow + m * 16 + j) * Nb + ccol + n * 16] = acc[m][n][j];
}

// ---------------------------------------------------------------------------
// Chunk-parallel banded attention, fused normalization; band-trimmed staging
// and PV (jc_hi); fused epilogue when nch==1, else partial to Ypart.
// ---------------------------------------------------------------------------
__global__ __launch_bounds__(256) void attn_chunk_kernel(
    const float* __restrict__ qg, const float* __restrict__ kv,
    const float* __restrict__ log_window, const float* __restrict__ log_r,
    const float* __restrict__ log_hscale,
    float* __restrict__ Ypart, __hip_bfloat16* __restrict__ Yb)
{
    int bid = blockIdx.x;                 // h*(128*NCH_MAX) + tile*NCH_MAX + slot
    int h    = bid / (128 * NCH_MAX);
    int rem  = bid - h * (128 * NCH_MAX);
    int tile = rem / NCH_MAX;
    int slot = rem - tile * NCH_MAX;
    int i0 = tile * TI;
    int t = threadIdx.x;

    float w = expf(log_window[h]) + 1.f;
    float r = expf(log_r[h]) + 1.f;
    int dmax = (int)ceilf(w) - 1;
    int jstart = i0 - dmax; if (jstart < 0) jstart = 0;
    int nch = (i0 + TI - jstart + DC - 1) / DC;
    if (slot >= nch) return;
    int j0 = jstart + slot * DC;

    int jc_hi  = min(DC, i0 + TI - j0);   // rows >= jc_hi are outside every band
    int jc_pad = (jc_hi + 3) & ~3;        // pad to float4 PV groups
    int g4_hi  = jc_pad >> 2;

    __shared__ float Q_lds[TI][16];
    __shared__ float K_lds[DC][16];
    __shared__ float V_lds[DC][DVH];
    __shared__ float att_lds[TI][68];
    __shared__ float soft_lds[288];

    const float PI = 3.14159265358979f;
    for (int d = t; d <= dmax; d += 256)
        soft_lds[d] = 0.5f * (cosf(PI * (float)d / w) + 1.f);

    if (t < TI * 4) {
        int iq = t >> 2, c = (t & 3) * 4;
        float4 qv = *(const float4*)(qg + (size_t)(i0 + iq) * QGN + h * QGW + c);
        float s = qv.x*qv.x + qv.y*qv.y + qv.z*qv.z + qv.w*qv.w;
        s += __shfl_xor(s, 1); s += __shfl_xor(s, 2);
        float inv = 1.f / fmaxf(sqrtf(s), 1e-12f);
        qv.x *= inv; qv.y *= inv; qv.z *= inv; qv.w *= inv;
        *(float4*)&Q_lds[iq][c] = qv;
    }
    // K stage + normalize (only rows < jc_hi are meaningful; beyond masked)
    {
        int jr = t >> 2, c = (t & 3) * 4;
        int j = j0 + jr;
        if (jr < jc_hi) {
            float4 kx = make_float4(0.f, 0.f, 0.f, 0.f);
            if (j < N_TOK)
                kx = *(const float4*)(kv + (size_t)j * QGN + h * QGW + c);
            float s = kx.x*kx.x + kx.y*kx.y + kx.z*kx.z + kx.w*kx.w;
            s += __shfl_xor(s, 1); s += __shfl_xor(s, 2);
            float inv = 1.f / fmaxf(sqrtf(s), 1e-12f);
            kx.x *= inv; kx.y *= inv; kx.z *= inv; kx.w *= inv;
            *(float4*)&K_lds[jr][c] = kx;
        }
    }
    // V stage + normalize (rows < jc_pad so PV partial groups read defined data)
    #pragma unroll
    for (int kk = 0; kk < 4; ++kk) {
        int f = t + kk * 256;
        int jc = f >> 4, c = (f & 15) * 4;
        int j = j0 + jc;
        if (jc < jc_pad) {
            float4 vx = make_float4(0.f, 0.f, 0.f, 0.f);
            if (j < N_TOK)
                vx = *(const float4*)(kv + (size_t)j * QGN + h * QGW + DKQ + c);
            float s = vx.x*vx.x + vx.y*vx.y + vx.z*vx.z + vx.w*vx.w;
            s += __shfl_xor(s, 1); s += __shfl_xor(s, 2);
            s += __shfl_xor(s, 4); s += __shfl_xor(s, 8);
            float inv = 1.f / fmaxf(sqrtf(s), 1e-12f);
            vx.x *= inv; vx.y *= inv; vx.z *= inv; vx.w *= inv;
            *(float4*)&V_lds[jc][c] = vx;
        }
    }
    __syncthreads();

    int i_loc = t & 31;
    int jgrp  = t >> 5;
    int i_glob = i0 + i_loc;
    float q[16];
    #pragma unroll
    for (int c = 0; c < 16; ++c) q[c] = Q_lds[i_loc][c];

    // scores for jc < jc_pad (att for jc in [jc_hi, jc_pad) is 0 via valid mask:
    // j >= i0+TI there => d < 0)
    #pragma unroll
    for (int jj = 0; jj < 8; ++jj) {
        int jc = jgrp * 8 + jj;
        if (jc >= jc_pad) break;
        int j = j0 + jc;
        int d = i_glob - j;
        float sim = 0.f;
        #pragma unroll
        for (int c4 = 0; c4 < 4; ++c4) {
            float4 kk4 = *(const float4*)&K_lds[jc][c4 * 4];
            sim += q[c4*4+0]*kk4.x + q[c4*4+1]*kk4.y
                 + q[c4*4+2]*kk4.z + q[c4*4+3]*kk4.w;
        }
        float a = fmaxf(1.f - r * (1.f - sim), 0.f);
        int dc = min(max(d, 0), dmax);
        bool valid = (d >= 0) && (d <= dmax);
        att_lds[i_loc][jc] = valid ? a * a * soft_lds[dc] : 0.f;
    }
    __syncthreads();

    int wv = t >> 6, ihalf = (t >> 5) & 1, dvp = t & 31;
    int ib = wv * 8 + ihalf * 4;
    float acc[4][2] = {};

    for (int g4 = 0; g4 < g4_hi; ++g4) {
        int jc0 = g4 * 4;
        float4 am[4];
        #pragma unroll
        for (int m = 0; m < 4; ++m)
            am[m] = *(const float4*)&att_lds[ib + m][jc0];
        float2 v0 = *(const float2*)&V_lds[jc0 + 0][dvp * 2];
        float2 v1 = *(const float2*)&V_lds[jc0 + 1][dvp * 2];
        float2 v2 = *(const float2*)&V_lds[jc0 + 2][dvp * 2];
        float2 v3 = *(const float2*)&V_lds[jc0 + 3][dvp * 2];
        #pragma unroll
        for (int m = 0; m < 4; ++m) {
            acc[m][0] += am[m].x * v0.x + am[m].y * v1.x
                       + am[m].z * v2.x + am[m].w * v3.x;
            acc[m][1] += am[m].x * v0.y + am[m].y * v1.y
                       + am[m].z * v2.y + am[m].w * v3.y;
        }
    }

    if (nch == 1) {
        float hs = expf(log_hscale[h]);
        #pragma unroll
        for (int m = 0; m < 4; ++m) {
            float ss = acc[m][0]*acc[m][0] + acc[m][1]*acc[m][1];
            #pragma unroll
            for (int off = 16; off; off >>= 1) ss += __shfl_xor(ss, off);
            float norm = sqrtf(ss);
            float scale = tanhf(norm) / fmaxf(norm, 1e-12f);
            int i = i0 + ib + m;
            float2 g2 = *(const float2*)(qg + (size_t)i * QGN + h * QGW + DKQ + dvp * 2);
            float gate0 = tanhf(g2.x / (1.f + expf(-g2.x)));
            float gate1 = tanhf(g2.y / (1.f + expf(-g2.y)));
            __hip_bfloat16 ob[2] = { __float2bfloat16(acc[m][0] * scale * gate0 * hs),
                                     __float2bfloat16(acc[m][1] * scale * gate1 * hs) };
            *(ushort2*)(Yb + (size_t)i * HD + h * DVH + dvp * 2) = *(const ushort2*)ob;
        }
    } else {
        #pragma unroll
        for (int m = 0; m < 4; ++m) {
            int i = i0 + ib + m;
            float2 st = make_float2(acc[m][0], acc[m][1]);
            *(float2*)(Ypart + ((size_t)slot * N_TOK + i) * HD + h * DVH + dvp * 2) = st;
        }
    }
}

// ---------------------------------------------------------------------------
// Epilogue for multi-chunk rows only (h in {5,6,7}). One wave per (h, i).
// ---------------------------------------------------------------------------
__global__ __launch_bounds__(256) void attn_epilogue_kernel(
    const float* __restrict__ Ypart, const float* __restrict__ qg,
    const float* __restrict__ log_window, const float* __restrict__ log_hscale,
    __hip_bfloat16* __restrict__ Y)
{
    int wv = threadIdx.x >> 6, lane = threadIdx.x & 63;
    int gid = 5 * N_TOK + blockIdx.x * 4 + wv;   // h*N_TOK + i
    int h = gid >> 12;
    int i = gid & (N_TOK - 1);

    float w  = expf(log_window[h]) + 1.f;
    int dmax = (int)ceilf(w) - 1;
    int i0 = i & ~(TI - 1);
    int jstart = i0 - dmax; if (jstart < 0) jstart = 0;
    int nch = (i0 + TI - jstart + DC - 1) / DC;
    if (nch < 2) return;

    float hs = expf(log_hscale[h]);
    size_t base = (size_t)i * HD + h * DVH + lane;
    float a = 0.f;
    for (int c = 0; c < nch; ++c)
        a += Ypart[(size_t)c * N_TOK * HD + base];

    float g = qg[(size_t)i * QGN + h * QGW + DKQ + lane];
    float gate = tanhf(g / (1.f + expf(-g)));

    float ss = a * a;
    #pragma unroll
    for (int off = 32; off; off >>= 1) ss += __shfl_xor(ss, off);
    float norm = sqrtf(ss);
    float scale = tanhf(norm) / fmaxf(norm, 1e-12f);

    float o = a * scale * gate * hs;
    Y[(size_t)i * HD + h * DVH + lane] = __float2bfloat16(o);
}

// ---------------------------------------------------------------------------
extern "C" void kernel_launch(void* const* d_in, const int* in_sizes, int n_in,
                              void* d_out, int out_size, void* d_ws, size_t ws_size,
                              hipStream_t stream)
{
    const float* tokens     = (const float*)d_in[0];
    const float* w_qg       = (const float*)d_in[1];
    const float* w_kv       = (const float*)d_in[2];
    const float* w_out      = (const float*)d_in[3];
    const float* log_window = (const float*)d_in[4];
    const float* log_r      = (const float*)d_in[5];
    const float* log_hscale = (const float*)d_in[6];
    float* out = (float*)d_out;

    char* ws = (char*)d_ws;
    float* qg = (float*)ws;            ws += (size_t)N_TOK * QGN * 4;
    float* kv = (float*)ws;            ws += (size_t)N_TOK * QGN * 4;
    __hip_bfloat16* tokB  = (__hip_bfloat16*)ws; ws += (size_t)N_TOK * D_MODEL * 2;
    __hip_bfloat16* wqgT  = (__hip_bfloat16*)ws; ws += (size_t)QGN * D_MODEL * 2;
    __hip_bfloat16* wkvT  = (__hip_bfloat16*)ws; ws += (size_t)QGN * D_MODEL * 2;
    __hip_bfloat16* woutT = (__hip_bfloat16*)ws; ws += (size_t)D_MODEL * HD * 2;
    __hip_bfloat16* Yb    = (__hip_bfloat16*)ws; ws += (size_t)N_TOK * HD * 2;
    float* Ypart = (float*)ws;         ws += (size_t)NCH_MAX * N_TOK * HD * 4;

    // 0) pack: tokens cast + weight transposes
    pack_kernel<<<5888, 256, 0, stream>>>(tokens, w_qg, w_kv, w_out,
                                          tokB, wqgT, wkvT, woutT);
    // 1) qg / kv projection (dual-B, BN=64 -> 640 blocks)
    {
        dim3 grid(2 * (QGN / 64), N_TOK / 128);
        gemm_mfma<<<grid, 256, 0, stream>>>(tokB, wqgT, qg, wkvT, kv,
                                            QGN, D_MODEL, QGN / 64);
    }
    // 2) chunk-parallel attention (fused norm; fused epilogue when nch==1)
    attn_chunk_kernel<<<NHEAD * (N_TOK / TI) * NCH_MAX, 256, 0, stream>>>(
        qg, kv, log_window, log_r, log_hscale, Ypart, Yb);
    // 3) epilogue for multi-chunk rows
    attn_epilogue_kernel<<<EPI_UNITS, 256, 0, stream>>>(
        Ypart, qg, log_window, log_hscale, Yb);
    // 4) out = Y @ w_out
    {
        dim3 grid(D_MODEL / 64, N_TOK / 128);
        gemm_mfma<<<grid, 256, 0, stream>>>(Yb, woutT, out, woutT, out,
                                            D_MODEL, HD, D_MODEL / 64);
    }
}

// Round 13
// 78.324 us; speedup vs baseline: 6.4569x; 1.0300x over previous
//
#include <hip/hip_runtime.h>
#include <hip/hip_bf16.h>
#include <math.h>

#define N_TOK 4096
#define D_MODEL 1024
#define NHEAD 8
#define DKQ 16
#define DVH 64
#define QGW 80   // DK+DV columns per head
#define QGN 640  // H * 80
#define HD  512  // H * DV
#define TI  32   // attention: i-rows per tile
#define DC  64   // attention: j-chunk width
#define NCH_MAX 5
#define EPI_UNITS (3 * N_TOK / 4)   // h in {5,6,7}, 4 rows per unit

typedef __attribute__((ext_vector_type(8))) short short8;
typedef __attribute__((ext_vector_type(4))) float f32x4;

#define GLOAD_LDS16(gp, lp) \
  __builtin_amdgcn_global_load_lds((const __attribute__((address_space(1))) void*)(gp), \
                                   (__attribute__((address_space(3))) void*)(lp), 16, 0, 0)

// ---------------------------------------------------------------------------
// pack: tokens fp32->bf16 cast (grid-stride, blocks [0,1024)) + 3 weight
// transpose+casts (blocks [1024, 2816)).
// ---------------------------------------------------------------------------
__global__ __launch_bounds__(256) void pack_kernel(
    const float* __restrict__ tokens, const float* __restrict__ w_qg,
    const float* __restrict__ w_kv, const float* __restrict__ w_out,
    __hip_bfloat16* __restrict__ tokB, __hip_bfloat16* __restrict__ wqgT,
    __hip_bfloat16* __restrict__ wkvT, __hip_bfloat16* __restrict__ woutT)
{
    __shared__ float tile[32][33];
    int b = blockIdx.x;
    int t = threadIdx.x;

    if (b < 1024) {                       // tokens cast, 4 float4 per thread
        #pragma unroll
        for (int it = 0; it < 4; ++it) {
            int i4 = b * 256 + t + it * 262144;
            float4 v = ((const float4*)tokens)[i4];
            __hip_bfloat16 o[4] = { __float2bfloat16(v.x), __float2bfloat16(v.y),
                                    __float2bfloat16(v.z), __float2bfloat16(v.w) };
            ((ushort4*)tokB)[i4] = *(const ushort4*)o;
        }
        return;
    }

    const float* in; __hip_bfloat16* outp; int R, C, tb;
    b -= 1024;
    if (b < 640)       { in = w_qg;  outp = wqgT;  R = 1024; C = 640;  tb = b; }
    else if (b < 1280) { in = w_kv;  outp = wkvT;  R = 1024; C = 640;  tb = b - 640; }
    else               { in = w_out; outp = woutT; R = 512;  C = 1024; tb = b - 1280; }
    int ctiles = C / 32;
    int bx = (tb % ctiles) * 32;
    int by = (tb / ctiles) * 32;
    int tx = t & 31, ty = t >> 5;

    #pragma unroll
    for (int j = 0; j < 32; j += 8)
        tile[j + ty][tx] = in[(size_t)(by + j + ty) * C + bx + tx];
    __syncthreads();
    #pragma unroll
    for (int j = 0; j < 32; j += 8)
        outp[(size_t)(bx + j + ty) * R + by + tx] =
            __float2bfloat16(tile[tx][j + ty]);
}

// ---------------------------------------------------------------------------
// bf16 MFMA GEMM, 128x64 tile, BK=64 double-buffered, XCD-chunked swizzle:
// blocks sharing an A-panel (same bm) are concentrated on one XCD so the
// 256KB panel stays in that XCD's L2. Requires (gridDim.x*gridDim.y)%8==0.
// ---------------------------------------------------------------------------
__global__ __launch_bounds__(256) void gemm_mfma(
    const __hip_bfloat16* __restrict__ A,
    const __hip_bfloat16* __restrict__ Bt0, float* __restrict__ C0,
    const __hip_bfloat16* __restrict__ Bt1, float* __restrict__ C1,
    int Nb, int K, int ntiles_n)
{
    __shared__ __hip_bfloat16 As[2][2][128 * 32];   // 32 KB
    __shared__ __hip_bfloat16 Bs[2][2][64 * 32];    // 16 KB

    int t = threadIdx.x;
    int l = t & 63;
    int w = t >> 6;
    int wr = w >> 1, wc = w & 1;

    // XCD-chunked bijective remap (m204): hw-id -> work-id
    int nwg  = gridDim.x * gridDim.y;
    int flat = blockIdx.y * gridDim.x + blockIdx.x;
    int q    = nwg >> 3;                      // nwg / 8, nwg % 8 == 0
    int rid  = (flat & 7) * q + (flat >> 3);
    int bnt  = rid % gridDim.x;
    int bmt  = rid / gridDim.x;

    const __hip_bfloat16* Bt = Bt0;
    float* C = C0;
    if (bnt >= ntiles_n) { Bt = Bt1; C = C1; bnt -= ntiles_n; }
    int bm = bmt * 128;
    int bn = bnt * 64;

    int srow = t >> 2;
    int skc  = (t & 3) * 8;
    const __hip_bfloat16* ga0 = A + (size_t)(bm + srow) * K + skc;
    const __hip_bfloat16* ga1 = A + (size_t)(bm + 64 + srow) * K + skc;
    const __hip_bfloat16* gb  = Bt + (size_t)(bn + srow) * K + skc;
    int ldst = (t & ~63) * 8;           // wave-uniform LDS base (elems)

#define STAGE(buf, k0) do { \
    GLOAD_LDS16(ga0 + (k0),      &As[buf][0][ldst]); \
    GLOAD_LDS16(ga1 + (k0),      &As[buf][0][2048 + ldst]); \
    GLOAD_LDS16(gb  + (k0),      &Bs[buf][0][ldst]); \
    GLOAD_LDS16(ga0 + (k0) + 32, &As[buf][1][ldst]); \
    GLOAD_LDS16(ga1 + (k0) + 32, &As[buf][1][2048 + ldst]); \
    GLOAD_LDS16(gb  + (k0) + 32, &Bs[buf][1][ldst]); } while (0)

    f32x4 acc[4][2] = {};

    int aro = (wr * 64 + (l & 15)) * 32 + (l >> 4) * 8;
    int bro = (wc * 32 + (l & 15)) * 32 + (l >> 4) * 8;

    int nk = K >> 6;                    // K / 64
    STAGE(0, 0);                        // prologue
    __syncthreads();

    int cur = 0;
    for (int it = 0; it < nk; ++it) {
        if (it + 1 < nk) STAGE(cur ^ 1, (it + 1) << 6);   // prefetch next

        #pragma unroll
        for (int kk = 0; kk < 2; ++kk) {
            short8 af[4], bf[2];
            #pragma unroll
            for (int m = 0; m < 4; ++m)
                af[m] = *(const short8*)&As[cur][kk][aro + m * 16 * 32];
            #pragma unroll
            for (int n = 0; n < 2; ++n)
                bf[n] = *(const short8*)&Bs[cur][kk][bro + n * 16 * 32];

            #pragma unroll
            for (int m = 0; m < 4; ++m)
                #pragma unroll
                for (int n = 0; n < 2; ++n)
                    acc[m][n] = __builtin_amdgcn_mfma_f32_16x16x32_bf16(
                                    af[m], bf[n], acc[m][n], 0, 0, 0);
        }
        __syncthreads();                // drains prefetch; next buf ready
        cur ^= 1;
    }
#undef STAGE

    int crow = bm + wr * 64 + (l >> 4) * 4;
    int ccol = bn + wc * 32 + (l & 15);
    #pragma unroll
    for (int m = 0; m < 4; ++m)
        #pragma unroll
        for (int n = 0; n < 2; ++n)
            #pragma unroll
            for (int j = 0; j < 4; ++j)
                C[(size_t)(crow + m * 16 + j) * Nb + ccol + n * 16] = acc[m][n][j];
}

// ---------------------------------------------------------------------------
// Chunk-parallel banded attention, fused normalization; band-trimmed staging
// and PV (jc_hi); fused epilogue when nch==1, else partial to Ypart.
// ---------------------------------------------------------------------------
__global__ __launch_bounds__(256) void attn_chunk_kernel(
    const float* __restrict__ qg, const float* __restrict__ kv,
    const float* __restrict__ log_window, const float* __restrict__ log_r,
    const float* __restrict__ log_hscale,
    float* __restrict__ Ypart, __hip_bfloat16* __restrict__ Yb)
{
    int bid = blockIdx.x;                 // h*(128*NCH_MAX) + tile*NCH_MAX + slot
    int h    = bid / (128 * NCH_MAX);
    int rem  = bid - h * (128 * NCH_MAX);
    int tile = rem / NCH_MAX;
    int slot = rem - tile * NCH_MAX;
    int i0 = tile * TI;
    int t = threadIdx.x;

    float w = expf(log_window[h]) + 1.f;
    float r = expf(log_r[h]) + 1.f;
    int dmax = (int)ceilf(w) - 1;
    int jstart = i0 - dmax; if (jstart < 0) jstart = 0;
    int nch = (i0 + TI - jstart + DC - 1) / DC;
    if (slot >= nch) return;
    int j0 = jstart + slot * DC;

    int jc_hi  = min(DC, i0 + TI - j0);   // rows >= jc_hi are outside every band
    int jc_pad = (jc_hi + 3) & ~3;        // pad to float4 PV groups
    int g4_hi  = jc_pad >> 2;

    __shared__ float Q_lds[TI][16];
    __shared__ float K_lds[DC][16];
    __shared__ float V_lds[DC][DVH];
    __shared__ float att_lds[TI][68];
    __shared__ float soft_lds[288];

    const float PI = 3.14159265358979f;
    for (int d = t; d <= dmax; d += 256)
        soft_lds[d] = 0.5f * (cosf(PI * (float)d / w) + 1.f);

    if (t < TI * 4) {
        int iq = t >> 2, c = (t & 3) * 4;
        float4 qv = *(const float4*)(qg + (size_t)(i0 + iq) * QGN + h * QGW + c);
        float s = qv.x*qv.x + qv.y*qv.y + qv.z*qv.z + qv.w*qv.w;
        s += __shfl_xor(s, 1); s += __shfl_xor(s, 2);
        float inv = 1.f / fmaxf(sqrtf(s), 1e-12f);
        qv.x *= inv; qv.y *= inv; qv.z *= inv; qv.w *= inv;
        *(float4*)&Q_lds[iq][c] = qv;
    }
    // K stage + normalize (only rows < jc_hi are meaningful)
    {
        int jr = t >> 2, c = (t & 3) * 4;
        int j = j0 + jr;
        if (jr < jc_hi) {
            float4 kx = make_float4(0.f, 0.f, 0.f, 0.f);
            if (j < N_TOK)
                kx = *(const float4*)(kv + (size_t)j * QGN + h * QGW + c);
            float s = kx.x*kx.x + kx.y*kx.y + kx.z*kx.z + kx.w*kx.w;
            s += __shfl_xor(s, 1); s += __shfl_xor(s, 2);
            float inv = 1.f / fmaxf(sqrtf(s), 1e-12f);
            kx.x *= inv; kx.y *= inv; kx.z *= inv; kx.w *= inv;
            *(float4*)&K_lds[jr][c] = kx;
        }
    }
    // V stage + normalize (rows < jc_pad so PV partial groups read defined data)
    #pragma unroll
    for (int kk = 0; kk < 4; ++kk) {
        int f = t + kk * 256;
        int jc = f >> 4, c = (f & 15) * 4;
        int j = j0 + jc;
        if (jc < jc_pad) {
            float4 vx = make_float4(0.f, 0.f, 0.f, 0.f);
            if (j < N_TOK)
                vx = *(const float4*)(kv + (size_t)j * QGN + h * QGW + DKQ + c);
            float s = vx.x*vx.x + vx.y*vx.y + vx.z*vx.z + vx.w*vx.w;
            s += __shfl_xor(s, 1); s += __shfl_xor(s, 2);
            s += __shfl_xor(s, 4); s += __shfl_xor(s, 8);
            float inv = 1.f / fmaxf(sqrtf(s), 1e-12f);
            vx.x *= inv; vx.y *= inv; vx.z *= inv; vx.w *= inv;
            *(float4*)&V_lds[jc][c] = vx;
        }
    }
    __syncthreads();

    int i_loc = t & 31;
    int jgrp  = t >> 5;
    int i_glob = i0 + i_loc;
    float q[16];
    #pragma unroll
    for (int c = 0; c < 16; ++c) q[c] = Q_lds[i_loc][c];

    #pragma unroll
    for (int jj = 0; jj < 8; ++jj) {
        int jc = jgrp * 8 + jj;
        if (jc >= jc_pad) break;
        int j = j0 + jc;
        int d = i_glob - j;
        float sim = 0.f;
        #pragma unroll
        for (int c4 = 0; c4 < 4; ++c4) {
            float4 kk4 = *(const float4*)&K_lds[jc][c4 * 4];
            sim += q[c4*4+0]*kk4.x + q[c4*4+1]*kk4.y
                 + q[c4*4+2]*kk4.z + q[c4*4+3]*kk4.w;
        }
        float a = fmaxf(1.f - r * (1.f - sim), 0.f);
        int dc = min(max(d, 0), dmax);
        bool valid = (d >= 0) && (d <= dmax);
        att_lds[i_loc][jc] = valid ? a * a * soft_lds[dc] : 0.f;
    }
    __syncthreads();

    int wv = t >> 6, ihalf = (t >> 5) & 1, dvp = t & 31;
    int ib = wv * 8 + ihalf * 4;
    float acc[4][2] = {};

    for (int g4 = 0; g4 < g4_hi; ++g4) {
        int jc0 = g4 * 4;
        float4 am[4];
        #pragma unroll
        for (int m = 0; m < 4; ++m)
            am[m] = *(const float4*)&att_lds[ib + m][jc0];
        float2 v0 = *(const float2*)&V_lds[jc0 + 0][dvp * 2];
        float2 v1 = *(const float2*)&V_lds[jc0 + 1][dvp * 2];
        float2 v2 = *(const float2*)&V_lds[jc0 + 2][dvp * 2];
        float2 v3 = *(const float2*)&V_lds[jc0 + 3][dvp * 2];
        #pragma unroll
        for (int m = 0; m < 4; ++m) {
            acc[m][0] += am[m].x * v0.x + am[m].y * v1.x
                       + am[m].z * v2.x + am[m].w * v3.x;
            acc[m][1] += am[m].x * v0.y + am[m].y * v1.y
                       + am[m].z * v2.y + am[m].w * v3.y;
        }
    }

    if (nch == 1) {
        float hs = expf(log_hscale[h]);
        #pragma unroll
        for (int m = 0; m < 4; ++m) {
            float ss = acc[m][0]*acc[m][0] + acc[m][1]*acc[m][1];
            #pragma unroll
            for (int off = 16; off; off >>= 1) ss += __shfl_xor(ss, off);
            float norm = sqrtf(ss);
            float scale = tanhf(norm) / fmaxf(norm, 1e-12f);
            int i = i0 + ib + m;
            float2 g2 = *(const float2*)(qg + (size_t)i * QGN + h * QGW + DKQ + dvp * 2);
            float gate0 = tanhf(g2.x / (1.f + expf(-g2.x)));
            float gate1 = tanhf(g2.y / (1.f + expf(-g2.y)));
            __hip_bfloat16 ob[2] = { __float2bfloat16(acc[m][0] * scale * gate0 * hs),
                                     __float2bfloat16(acc[m][1] * scale * gate1 * hs) };
            *(ushort2*)(Yb + (size_t)i * HD + h * DVH + dvp * 2) = *(const ushort2*)ob;
        }
    } else {
        #pragma unroll
        for (int m = 0; m < 4; ++m) {
            int i = i0 + ib + m;
            float2 st = make_float2(acc[m][0], acc[m][1]);
            *(float2*)(Ypart + ((size_t)slot * N_TOK + i) * HD + h * DVH + dvp * 2) = st;
        }
    }
}

// ---------------------------------------------------------------------------
// Epilogue for multi-chunk rows only (h in {5,6,7}). One wave per (h, i).
// ---------------------------------------------------------------------------
__global__ __launch_bounds__(256) void attn_epilogue_kernel(
    const float* __restrict__ Ypart, const float* __restrict__ qg,
    const float* __restrict__ log_window, const float* __restrict__ log_hscale,
    __hip_bfloat16* __restrict__ Y)
{
    int wv = threadIdx.x >> 6, lane = threadIdx.x & 63;
    int gid = 5 * N_TOK + blockIdx.x * 4 + wv;   // h*N_TOK + i
    int h = gid >> 12;
    int i = gid & (N_TOK - 1);

    float w  = expf(log_window[h]) + 1.f;
    int dmax = (int)ceilf(w) - 1;
    int i0 = i & ~(TI - 1);
    int jstart = i0 - dmax; if (jstart < 0) jstart = 0;
    int nch = (i0 + TI - jstart + DC - 1) / DC;
    if (nch < 2) return;

    float hs = expf(log_hscale[h]);
    size_t base = (size_t)i * HD + h * DVH + lane;
    float a = 0.f;
    for (int c = 0; c < nch; ++c)
        a += Ypart[(size_t)c * N_TOK * HD + base];

    float g = qg[(size_t)i * QGN + h * QGW + DKQ + lane];
    float gate = tanhf(g / (1.f + expf(-g)));

    float ss = a * a;
    #pragma unroll
    for (int off = 32; off; off >>= 1) ss += __shfl_xor(ss, off);
    float norm = sqrtf(ss);
    float scale = tanhf(norm) / fmaxf(norm, 1e-12f);

    float o = a * scale * gate * hs;
    Y[(size_t)i * HD + h * DVH + lane] = __float2bfloat16(o);
}

// ---------------------------------------------------------------------------
extern "C" void kernel_launch(void* const* d_in, const int* in_sizes, int n_in,
                              void* d_out, int out_size, void* d_ws, size_t ws_size,
                              hipStream_t stream)
{
    const float* tokens     = (const float*)d_in[0];
    const float* w_qg       = (const float*)d_in[1];
    const float* w_kv       = (const float*)d_in[2];
    const float* w_out      = (const float*)d_in[3];
    const float* log_window = (const float*)d_in[4];
    const float* log_r      = (const float*)d_in[5];
    const float* log_hscale = (const float*)d_in[6];
    float* out = (float*)d_out;

    char* ws = (char*)d_ws;
    float* qg = (float*)ws;            ws += (size_t)N_TOK * QGN * 4;
    float* kv = (float*)ws;            ws += (size_t)N_TOK * QGN * 4;
    __hip_bfloat16* tokB  = (__hip_bfloat16*)ws; ws += (size_t)N_TOK * D_MODEL * 2;
    __hip_bfloat16* wqgT  = (__hip_bfloat16*)ws; ws += (size_t)QGN * D_MODEL * 2;
    __hip_bfloat16* wkvT  = (__hip_bfloat16*)ws; ws += (size_t)QGN * D_MODEL * 2;
    __hip_bfloat16* woutT = (__hip_bfloat16*)ws; ws += (size_t)D_MODEL * HD * 2;
    __hip_bfloat16* Yb    = (__hip_bfloat16*)ws; ws += (size_t)N_TOK * HD * 2;
    float* Ypart = (float*)ws;         ws += (size_t)NCH_MAX * N_TOK * HD * 4;

    // 0) pack: tokens cast (grid-stride) + weight transposes
    pack_kernel<<<2816, 256, 0, stream>>>(tokens, w_qg, w_kv, w_out,
                                          tokB, wqgT, wkvT, woutT);
    // 1) qg / kv projection (dual-B, BN=64 -> 640 blocks, XCD-swizzled)
    {
        dim3 grid(2 * (QGN / 64), N_TOK / 128);
        gemm_mfma<<<grid, 256, 0, stream>>>(tokB, wqgT, qg, wkvT, kv,
                                            QGN, D_MODEL, QGN / 64);
    }
    // 2) chunk-parallel attention (fused norm; fused epilogue when nch==1)
    attn_chunk_kernel<<<NHEAD * (N_TOK / TI) * NCH_MAX, 256, 0, stream>>>(
        qg, kv, log_window, log_r, log_hscale, Ypart, Yb);
    // 3) epilogue for multi-chunk rows
    attn_epilogue_kernel<<<EPI_UNITS, 256, 0, stream>>>(
        Ypart, qg, log_window, log_hscale, Yb);
    // 4) out = Y @ w_out (512 blocks, XCD-swizzled)
    {
        dim3 grid(D_MODEL / 64, N_TOK / 128);
        gemm_mfma<<<grid, 256, 0, stream>>>(Yb, woutT, out, woutT, out,
                                            D_MODEL, HD, D_MODEL / 64);
    }
}